// Round 6
// baseline (634.662 us; speedup 1.0000x reference)
//
#include <hip/hip_runtime.h>

#define LDIM 320
#define CZ 128
#define NH 4
#define CH 32
#define SCALE_QK 0.17677669529663687f  // 1/sqrt(32)
#define LN_EPS 1e-5f

typedef __attribute__((ext_vector_type(8))) short bf16x8;
typedef __attribute__((ext_vector_type(4))) float f32x4;

__device__ __forceinline__ unsigned int pack_bf2(float a, float b) {
  unsigned int ua = __float_as_uint(a);
  unsigned int ub = __float_as_uint(b);
  unsigned int ra = (ua + 0x7fffu + ((ua >> 16) & 1u)) >> 16;   // RNE bf16
  unsigned int rb = (ub + 0x7fffu + ((ub >> 16) & 1u)) >> 16;
  return (ra & 0xffffu) | (rb << 16);
}

__device__ __forceinline__ unsigned short f2bf(float a) {
  unsigned int ua = __float_as_uint(a);
  return (unsigned short)((ua + 0x7fffu + ((ua >> 16) & 1u)) >> 16);
}

__device__ __forceinline__ float bf2f(unsigned short u) {
  return __uint_as_float(((unsigned int)u) << 16);
}

// ---------------------------------------------------------------------------
// Kernel 0: weight prep. Wt[576][128] bf16 = [Wq*scale|Wk|Wv|Wg|Wb|0]^T;
// Woutt[128][128] bf16 = Wout^T. SCALE_QK folded into Wq (exact: Q=z@Wq).
// ---------------------------------------------------------------------------
__global__ __launch_bounds__(256) void k_prep(
    const float* __restrict__ Wq, const float* __restrict__ Wk,
    const float* __restrict__ Wv, const float* __restrict__ Wb,
    const float* __restrict__ Wg, const float* __restrict__ Wout,
    unsigned short* __restrict__ Wt, unsigned short* __restrict__ Woutt)
{
  __shared__ __attribute__((aligned(16))) unsigned short buf[64 * 136];
  const int t = threadIdx.x, bid = blockIdx.x;
  const bool isOut = (bid >= 9);
  const int n0 = isOut ? (bid - 9) * 64 : bid * 64;
  const int nl = t & 63;
  const int n = n0 + nl;
#pragma unroll 8
  for (int it = 0; it < 32; ++it) {
    const int k = (t >> 6) + 4 * it;
    float v;
    if (isOut)        v = Wout[k * 128 + n];
    else if (n < 128) v = Wq[k * 128 + n] * SCALE_QK;
    else if (n < 256) v = Wk[k * 128 + n - 128];
    else if (n < 384) v = Wv[k * 128 + n - 256];
    else if (n < 512) v = Wg[k * 128 + n - 384];
    else if (n < 516) v = Wb[k * 4 + n - 512];
    else              v = 0.f;
    buf[nl * 136 + k] = f2bf(v);
  }
  __syncthreads();
  unsigned short* dst = isOut ? Woutt : Wt;
#pragma unroll
  for (int it = 0; it < 4; ++it) {
    const int idx = t + 256 * it;
    const int rr = idx >> 4, ck = idx & 15;
    const uint4 d = *(const uint4*)&buf[rr * 136 + ck * 8];
    *(uint4*)(dst + (size_t)(n0 + rr) * 128 + ck * 8) = d;
  }
}

// ---------------------------------------------------------------------------
// Kernel 1: fused LayerNorm + all projections, bf16 MFMA GEMM.
// One block per 128-row M-tile (grid 800). V written TRANSPOSED per (i,h)
// as Vtg[c][k] (8B packed stores over r). Bh = bias + res_mask(-inf) folded.
// ---------------------------------------------------------------------------
__global__ __launch_bounds__(256) void k_lnproj(
    const float* __restrict__ z, const float* __restrict__ gamma,
    const float* __restrict__ beta, const unsigned short* __restrict__ Wt,
    const int* __restrict__ rmask,
    unsigned short* __restrict__ Qg, unsigned short* __restrict__ Kg,
    unsigned short* __restrict__ Vtg, unsigned short* __restrict__ Gg,
    float* __restrict__ Bh)
{
  __shared__ __attribute__((aligned(16))) unsigned short As[128 * 136]; // 34.8KB
  const int t = threadIdx.x;
  const int m0 = blockIdx.x * 128;
  const int rlane = t & 7;            // 8 lanes per row, 16 cols each

  const float* gp = gamma + rlane * 16;
  const float* bp = beta + rlane * 16;
  const float4 g0 = *(const float4*)(gp + 0);
  const float4 g1 = *(const float4*)(gp + 4);
  const float4 g2 = *(const float4*)(gp + 8);
  const float4 g3 = *(const float4*)(gp + 12);
  const float4 b0 = *(const float4*)(bp + 0);
  const float4 b1 = *(const float4*)(bp + 4);
  const float4 b2 = *(const float4*)(bp + 8);
  const float4 b3 = *(const float4*)(bp + 12);

  // ---- stage z -> LN -> bf16 As, coalesced (8 lanes/row) ----
#pragma unroll
  for (int rr = 0; rr < 4; ++rr) {
    const int row = rr * 32 + (t >> 3);
    const float* zp = z + (size_t)(m0 + row) * CZ + rlane * 16;
    const float4 x0 = *(const float4*)(zp + 0);
    const float4 x1 = *(const float4*)(zp + 4);
    const float4 x2 = *(const float4*)(zp + 8);
    const float4 x3 = *(const float4*)(zp + 12);
    float s  = x0.x + x0.y + x0.z + x0.w + x1.x + x1.y + x1.z + x1.w +
               x2.x + x2.y + x2.z + x2.w + x3.x + x3.y + x3.z + x3.w;
    float ss = x0.x*x0.x + x0.y*x0.y + x0.z*x0.z + x0.w*x0.w +
               x1.x*x1.x + x1.y*x1.y + x1.z*x1.z + x1.w*x1.w +
               x2.x*x2.x + x2.y*x2.y + x2.z*x2.z + x2.w*x2.w +
               x3.x*x3.x + x3.y*x3.y + x3.z*x3.z + x3.w*x3.w;
    s  += __shfl_xor(s, 1);  ss += __shfl_xor(ss, 1);
    s  += __shfl_xor(s, 2);  ss += __shfl_xor(ss, 2);
    s  += __shfl_xor(s, 4);  ss += __shfl_xor(ss, 4);
    const float mu  = s * (1.f / 128.f);
    const float var = ss * (1.f / 128.f) - mu * mu;
    const float rs  = rsqrtf(var + LN_EPS);
    uint4 u0, u1;
    u0.x = pack_bf2((x0.x - mu) * rs * g0.x + b0.x, (x0.y - mu) * rs * g0.y + b0.y);
    u0.y = pack_bf2((x0.z - mu) * rs * g0.z + b0.z, (x0.w - mu) * rs * g0.w + b0.w);
    u0.z = pack_bf2((x1.x - mu) * rs * g1.x + b1.x, (x1.y - mu) * rs * g1.y + b1.y);
    u0.w = pack_bf2((x1.z - mu) * rs * g1.z + b1.z, (x1.w - mu) * rs * g1.w + b1.w);
    u1.x = pack_bf2((x2.x - mu) * rs * g2.x + b2.x, (x2.y - mu) * rs * g2.y + b2.y);
    u1.y = pack_bf2((x2.z - mu) * rs * g2.z + b2.z, (x2.w - mu) * rs * g2.w + b2.w);
    u1.z = pack_bf2((x3.x - mu) * rs * g3.x + b3.x, (x3.y - mu) * rs * g3.y + b3.y);
    u1.w = pack_bf2((x3.z - mu) * rs * g3.z + b3.z, (x3.w - mu) * rs * g3.w + b3.w);
    unsigned short* dst = &As[row * 136 + rlane * 16];
    *(uint4*)(dst + 0) = u0;
    *(uint4*)(dst + 8) = u1;
  }
  __syncthreads();

  const int w = t >> 6, lane = t & 63;
  const int m16 = lane & 15, qd = lane >> 4;
  const f32x4 z4 = {0.f, 0.f, 0.f, 0.f};

  // ---- preload A-frags once ----
  bf16x8 af[2][4];
#pragma unroll
  for (int ks = 0; ks < 4; ++ks) {
    af[0][ks] = *(const bf16x8*)&As[(w * 32 + m16) * 136 + ks * 32 + qd * 8];
    af[1][ks] = *(const bf16x8*)&As[(w * 32 + 16 + m16) * 136 + ks * 32 + qd * 8];
  }

  // ---- 8 output n-tiles (Q/K/V/G), B-frags from global ----
  for (int ntile = 0; ntile < 8; ++ntile) {
    f32x4 acc[2][4];
#pragma unroll
    for (int sub = 0; sub < 2; ++sub)
#pragma unroll
      for (int nt = 0; nt < 4; ++nt) acc[sub][nt] = z4;
#pragma unroll
    for (int ks = 0; ks < 4; ++ks) {
#pragma unroll
      for (int nt = 0; nt < 4; ++nt) {
        const bf16x8 bf = *(const bf16x8*)(
            Wt + (size_t)(ntile * 64 + nt * 16 + m16) * 128 + ks * 32 + qd * 8);
        acc[0][nt] = __builtin_amdgcn_mfma_f32_16x16x32_bf16(af[0][ks], bf, acc[0][nt], 0, 0, 0);
        acc[1][nt] = __builtin_amdgcn_mfma_f32_16x16x32_bf16(af[1][ks], bf, acc[1][nt], 0, 0, 0);
      }
    }
    if (ntile == 4 || ntile == 5) {
      // V tiles -> transposed layout Vtg[(i*4+h)*10240 + c*320 + k], 8B packed
#pragma unroll
      for (int sub = 0; sub < 2; ++sub) {
        const int p0 = m0 + w * 32 + sub * 16 + qd * 4;
        const int a = p0 / 320, bb = p0 - a * 320;
#pragma unroll
        for (int nt = 0; nt < 4; ++nt) {
          const int n = ntile * 64 + nt * 16 + m16;
          const int off = n & 127, hh = off >> 5, cc = off & 31;
          uint2 pk;
          pk.x = pack_bf2(acc[sub][nt][0], acc[sub][nt][1]);
          pk.y = pack_bf2(acc[sub][nt][2], acc[sub][nt][3]);
          *(uint2*)(Vtg + (size_t)(a * 4 + hh) * 10240 + (size_t)cc * 320 + bb) = pk;
        }
      }
    } else {
#pragma unroll
      for (int sub = 0; sub < 2; ++sub) {
#pragma unroll
        for (int r = 0; r < 4; ++r) {
          const int p = m0 + w * 32 + sub * 16 + qd * 4 + r;
          const int a = p / 320, bb = p - a * 320;
#pragma unroll
          for (int nt = 0; nt < 4; ++nt) {
            const int n = ntile * 64 + nt * 16 + m16;
            const int off = n & 127, hh = off >> 5, cc = off & 31;
            float val = acc[sub][nt][r];
            if (ntile >= 6) val = 1.f / (1.f + __expf(-val));  // sigmoid for G
            unsigned short* dst = (ntile < 2 ? Qg : (ntile < 4 ? Kg : Gg));
            dst[((size_t)(a * 4 + hh) * 320 + bb) * 32 + cc] = f2bf(val);
          }
        }
      }
    }
  }

  // ---- bias tile: Bh = bias + mask(-inf folded) ----
  {
    f32x4 acc0 = z4, acc1 = z4;
#pragma unroll
    for (int ks = 0; ks < 4; ++ks) {
      const bf16x8 bf = *(const bf16x8*)(
          Wt + (size_t)(512 + m16) * 128 + ks * 32 + qd * 8);
      acc0 = __builtin_amdgcn_mfma_f32_16x16x32_bf16(af[0][ks], bf, acc0, 0, 0, 0);
      acc1 = __builtin_amdgcn_mfma_f32_16x16x32_bf16(af[1][ks], bf, acc1, 0, 0, 0);
    }
    if (m16 < 4) {
#pragma unroll
      for (int r = 0; r < 4; ++r) {
        const int p0 = m0 + w * 32 + qd * 4 + r;
        const int k0 = p0 % 320, k1 = (p0 + 16) % 320;
        const float mk0 = rmask[k0] ? 0.f : -INFINITY;
        const float mk1 = rmask[k1] ? 0.f : -INFINITY;
        Bh[(size_t)m16 * 102400 + p0] = acc0[r] + mk0;
        Bh[(size_t)m16 * 102400 + p0 + 16] = acc1[r] + mk1;
      }
    }
  }
}

// ---------------------------------------------------------------------------
// Kernel 2: MFMA attention, barrier-free. Block=(i,h), 4 independent waves.
// K and V^T fragments straight from global (L1/L2-hot); only per-wave Ps LDS.
// ---------------------------------------------------------------------------
__global__ __launch_bounds__(256) void k_attn(
    const unsigned short* __restrict__ Qg, const unsigned short* __restrict__ Kg,
    const unsigned short* __restrict__ Vtg, const unsigned short* __restrict__ Gg,
    const float* __restrict__ Bh,
    unsigned short* __restrict__ Obg)
{
  __shared__ __attribute__((aligned(16))) unsigned short Ps[4][16 * 168];  // 21.5KB
  const int h = blockIdx.x, i = blockIdx.y;
  const int t = threadIdx.x;
  const size_t base = (size_t)(i * NH + h) * (LDIM * CH);

  const int w = t >> 6, lane = t & 63;
  const int m16 = lane & 15, qd = lane >> 4;
  const f32x4 z4 = {0.f, 0.f, 0.f, 0.f};

  for (int jt = w; jt < 20; jt += 4) {
    const bf16x8 qfrag =
        *(const bf16x8*)(Qg + base + (size_t)(jt * 16 + m16) * 32 + qd * 8);

    // ---- QK^T: 20 MFMAs; K B-frags from global (Q pre-scaled) ----
    f32x4 acc[20];
#pragma unroll
    for (int kt = 0; kt < 20; ++kt) {
      const bf16x8 kf =
          *(const bf16x8*)(Kg + base + (size_t)(kt * 16 + m16) * 32 + qd * 8);
      acc[kt] = __builtin_amdgcn_mfma_f32_16x16x32_bf16(qfrag, kf, z4, 0, 0, 0);
    }

    // ---- + (bias+mask), row max (C layout: row=qd*4+r, col=m16) ----
    const float* bp = Bh + (size_t)h * 102400 +
                      (size_t)(jt * 16 + qd * 4) * 320 + m16;
    float mx[4] = {-INFINITY, -INFINITY, -INFINITY, -INFINITY};
#pragma unroll
    for (int kt = 0; kt < 20; ++kt) {
#pragma unroll
      for (int r = 0; r < 4; ++r) {
        const float s = acc[kt][r] + bp[r * 320 + kt * 16];
        acc[kt][r] = s;
        mx[r] = fmaxf(mx[r], s);
      }
    }
#pragma unroll
    for (int r = 0; r < 4; ++r) {
      mx[r] = fmaxf(mx[r], __shfl_xor(mx[r], 1));
      mx[r] = fmaxf(mx[r], __shfl_xor(mx[r], 2));
      mx[r] = fmaxf(mx[r], __shfl_xor(mx[r], 4));
      mx[r] = fmaxf(mx[r], __shfl_xor(mx[r], 8));
    }
    float l[4] = {0.f, 0.f, 0.f, 0.f};
#pragma unroll
    for (int kt = 0; kt < 20; ++kt) {
#pragma unroll
      for (int r = 0; r < 4; ++r) {
        const float p = __expf(acc[kt][r] - mx[r]);
        acc[kt][r] = p;
        l[r] += p;
      }
    }
#pragma unroll
    for (int r = 0; r < 4; ++r) {
      l[r] += __shfl_xor(l[r], 1);
      l[r] += __shfl_xor(l[r], 2);
      l[r] += __shfl_xor(l[r], 4);
      l[r] += __shfl_xor(l[r], 8);
    }
    float rl[4];
#pragma unroll
    for (int r = 0; r < 4; ++r) rl[r] = 1.f / l[r];

    // ---- PV: per-wave P^ LDS round-trip (no barriers); V^T from global ----
    f32x4 accO0 = z4, accO1 = z4;
#pragma unroll
    for (int hh = 0; hh < 2; ++hh) {
#pragma unroll
      for (int kt2 = 0; kt2 < 10; ++kt2) {
        const int kt = hh * 10 + kt2;
#pragma unroll
        for (int r = 0; r < 4; ++r)
          Ps[w][(qd * 4 + r) * 168 + kt2 * 16 + m16] = f2bf(acc[kt][r] * rl[r]);
      }
#pragma unroll
      for (int ks = 0; ks < 5; ++ks) {
        const bf16x8 pf = *(const bf16x8*)&Ps[w][m16 * 168 + ks * 32 + qd * 8];
        const bf16x8 v0 = *(const bf16x8*)(
            Vtg + base + (size_t)m16 * 320 + hh * 160 + ks * 32 + qd * 8);
        const bf16x8 v1 = *(const bf16x8*)(
            Vtg + base + (size_t)(16 + m16) * 320 + hh * 160 + ks * 32 + qd * 8);
        accO0 = __builtin_amdgcn_mfma_f32_16x16x32_bf16(pf, v0, accO0, 0, 0, 0);
        accO1 = __builtin_amdgcn_mfma_f32_16x16x32_bf16(pf, v1, accO1, 0, 0, 0);
      }
    }

    // ---- epilogue: gate + store ----
#pragma unroll
    for (int r = 0; r < 4; ++r) {
      const int j = jt * 16 + qd * 4 + r;
      const float g0 = bf2f(Gg[base + (size_t)j * 32 + m16]);
      const float g1 = bf2f(Gg[base + (size_t)j * 32 + 16 + m16]);
      unsigned short* op = Obg + (size_t)(i * 320 + j) * 128 + h * 32;
      op[m16]      = f2bf(g0 * accO0[r]);
      op[16 + m16] = f2bf(g1 * accO1[r]);
    }
  }
}

// ---------------------------------------------------------------------------
// Kernel 3: output GEMM dz = Obg @ Woutt^T, * pair_mask. bf16 MFMA.
// (verified round 4, unchanged)
// ---------------------------------------------------------------------------
__global__ __launch_bounds__(256) void k_out(
    const unsigned short* __restrict__ Obg, const unsigned short* __restrict__ Woutt,
    const float* __restrict__ pm, float* __restrict__ out)
{
  __shared__ __attribute__((aligned(16))) unsigned short As[128 * 136];
  __shared__ __attribute__((aligned(16))) unsigned short Bs[64 * 136];
  const int t = threadIdx.x;
  const int ntile = blockIdx.x;   // 0..1
  const int m0 = blockIdx.y * 128;

#pragma unroll
  for (int it = 0; it < 8; ++it) {
    const int idx = t + 256 * it;
    const int rr = idx >> 4, ck = idx & 15;
    const uint4 d = *(const uint4*)(Obg + (size_t)(m0 + rr) * 128 + ck * 8);
    *(uint4*)&As[rr * 136 + ck * 8] = d;
  }
  {
    const unsigned short* wrow = Woutt + (size_t)ntile * 64 * 128;
#pragma unroll
    for (int it = 0; it < 4; ++it) {
      const int idx = t + 256 * it;
      const int n = idx >> 4, ck = idx & 15;
      const uint4 d = *(const uint4*)(wrow + n * 128 + ck * 8);
      *(uint4*)&Bs[n * 136 + ck * 8] = d;
    }
  }
  __syncthreads();

  const int w = t >> 6, lane = t & 63;
  const int m16 = lane & 15, qd = lane >> 4;
  const f32x4 z4 = {0.f, 0.f, 0.f, 0.f};
  f32x4 acc[2][4];
#pragma unroll
  for (int sub = 0; sub < 2; ++sub)
#pragma unroll
    for (int nt = 0; nt < 4; ++nt) acc[sub][nt] = z4;

#pragma unroll
  for (int ks = 0; ks < 4; ++ks) {
    const bf16x8 af0 = *(const bf16x8*)&As[(w * 32 + m16) * 136 + qd * 8 + ks * 32];
    const bf16x8 af1 = *(const bf16x8*)&As[(w * 32 + 16 + m16) * 136 + qd * 8 + ks * 32];
#pragma unroll
    for (int nt = 0; nt < 4; ++nt) {
      const bf16x8 bf = *(const bf16x8*)&Bs[(nt * 16 + m16) * 136 + qd * 8 + ks * 32];
      acc[0][nt] = __builtin_amdgcn_mfma_f32_16x16x32_bf16(af0, bf, acc[0][nt], 0, 0, 0);
      acc[1][nt] = __builtin_amdgcn_mfma_f32_16x16x32_bf16(af1, bf, acc[1][nt], 0, 0, 0);
    }
  }

#pragma unroll
  for (int sub = 0; sub < 2; ++sub) {
#pragma unroll
    for (int r = 0; r < 4; ++r) {
      const int p = m0 + w * 32 + sub * 16 + qd * 4 + r;
      const float m = pm[p];
      float* orow = out + (size_t)p * 128 + ntile * 64;
#pragma unroll
      for (int nt = 0; nt < 4; ++nt)
        orow[nt * 16 + m16] = acc[sub][nt][r] * m;
    }
  }
}

// ---------------------------------------------------------------------------
extern "C" void kernel_launch(void* const* d_in, const int* in_sizes, int n_in,
                              void* d_out, int out_size, void* d_ws, size_t ws_size,
                              hipStream_t stream)
{
  const float* z     = (const float*)d_in[0];
  const float* pmask = (const float*)d_in[1];
  const int*   rmask = (const int*)d_in[2];
  const float* gamma = (const float*)d_in[3];
  const float* beta  = (const float*)d_in[4];
  const float* Wq    = (const float*)d_in[5];
  const float* Wk    = (const float*)d_in[6];
  const float* Wv    = (const float*)d_in[7];
  const float* Wb    = (const float*)d_in[8];
  const float* Wg    = (const float*)d_in[9];
  const float* Wout  = (const float*)d_in[10];

  const size_t P = (size_t)LDIM * LDIM;        // 102400
  const size_t E = P * 128;                    // 13,107,200 elements
  char* ws = (char*)d_ws;
  unsigned short* Qg = (unsigned short*)ws;              // E bf16
  unsigned short* Kg = Qg + E;
  unsigned short* Vtg = Kg + E;                          // V transposed [i][h][c][k]
  unsigned short* Gg = Vtg + E;
  unsigned short* Obg = Gg + E;                          // E bf16
  unsigned short* Wt = Obg + E;                          // 576*128 bf16
  unsigned short* Woutt = Wt + 576 * 128;                // 128*128 bf16
  float* Bh = (float*)(Woutt + 128 * 128);               // 4*P fp32

  k_prep<<<dim3(11), 256, 0, stream>>>(Wq, Wk, Wv, Wb, Wg, Wout, Wt, Woutt);
  k_lnproj<<<dim3(800), 256, 0, stream>>>(z, gamma, beta, Wt, rmask,
                                          Qg, Kg, Vtg, Gg, Bh);
  k_attn<<<dim3(NH, LDIM), 256, 0, stream>>>(Qg, Kg, Vtg, Gg, Bh, Obg);
  k_out<<<dim3(2, 800), 256, 0, stream>>>(Obg, Woutt, pmask, (float*)d_out);
}